// Round 5
// baseline (265.922 us; speedup 1.0000x reference)
//
#include <hip/hip_runtime.h>
#include <stdint.h>

typedef __bf16 bf16x8 __attribute__((ext_vector_type(8)));
typedef float f32x4 __attribute__((ext_vector_type(4)));
typedef float f32x16 __attribute__((ext_vector_type(16)));

#define EPS 1e-5f

__device__ __forceinline__ float b2f(unsigned short u) {
    union { unsigned int i; float f; } c; c.i = ((unsigned int)u) << 16; return c.f;
}
__device__ __forceinline__ unsigned short f2b(float f) {
    union { float f; unsigned int i; } c; c.f = f;
    unsigned int i = c.i;
    return (unsigned short)((i + 0x7FFFu + ((i >> 16) & 1u)) >> 16);
}

// Canonicalize params to bf16: wt1 = lw^T [256][512]; rwb = rw [512][256];
// vec = {lb(256), g1(256), b1(256), rb(512), ga(512), ba(512)}
__global__ void k_params(const float* __restrict__ lw, const float* __restrict__ rw,
                         const float* __restrict__ lb, const float* __restrict__ g1,
                         const float* __restrict__ b1, const float* __restrict__ rb,
                         const float* __restrict__ ga, const float* __restrict__ ba,
                         unsigned short* __restrict__ wt1,
                         unsigned short* __restrict__ rwb,
                         unsigned short* __restrict__ vec) {
    int gid = blockIdx.x * 256 + threadIdx.x;
    if (gid < 131072) {
        int k = gid >> 8, n = gid & 255;
        wt1[n * 512 + k] = f2b(lw[gid]);
    } else if (gid < 262144) {
        int j = gid - 131072;
        rwb[j] = f2b(rw[j]);
    } else if (gid < 264448) {
        int j = gid - 262144;
        if (j < 256)       vec[j] = f2b(lb[j]);
        else if (j < 512)  vec[j] = f2b(g1[j - 256]);
        else if (j < 768)  vec[j] = f2b(b1[j - 512]);
        else if (j < 1280) vec[j] = f2b(rb[j - 768]);
        else if (j < 1792) vec[j] = f2b(ga[j - 1280]);
        else               vec[j] = f2b(ba[j - 1792]);
    }
}

// per-row LN stats of x2 (row length 256); one wave per row
__global__ __launch_bounds__(256) void k_stats(const float* __restrict__ x2,
                                               float2* __restrict__ stats) {
    int t = threadIdx.x, lane = t & 63, w = t >> 6;
    size_t row = (size_t)blockIdx.x * 4 + w;
    float4 f = *(const float4*)(x2 + row * 256 + lane * 4);
    float s = f.x + f.y + f.z + f.w;
    float q = f.x * f.x + f.y * f.y + f.z * f.z + f.w * f.w;
#pragma unroll
    for (int msk = 1; msk < 64; msk <<= 1) {
        s += __shfl_xor(s, msk, 64);
        q += __shfl_xor(q, msk, 64);
    }
    float mn = s * (1.0f / 256.0f);
    float rstd = rsqrtf(q * (1.0f / 256.0f) - mn * mn + EPS);
    if (lane == 0) stats[row] = make_float2(mn, rstd);
}

// ctx partial: ctxr[bh][chunk][d][e] = sum_{m in chunk} q[d,m]*E[e,m]
// grid 512 = bh(64) x chunk(8 of 512 tokens). 256 thr / 4 waves.
// MFMA 32x32x16_bf16 over token-K; E/Q staged channel-major bf16 in LDS.
__global__ __launch_bounds__(256) void k_ctx(const float* __restrict__ x2,
                                             const float2* __restrict__ stats,
                                             const unsigned short* __restrict__ vec,
                                             float* __restrict__ ctxr) {
    __shared__ f32x4 pool4[1056];                     // 16896 B
    unsigned short* E = (unsigned short*)pool4;       // [32 ch][132 tok]
    unsigned short* Q = E + 32 * 132;
    float* Racc = (float*)pool4;                      // [4][1024] after MFMA

    const int blk = blockIdx.x;
    const int bh = blk >> 3, chunk = blk & 7;
    const int b = bh >> 3, h = bh & 7;
    const int t = threadIdx.x;
    const int ch = t & 31, tk2 = t >> 5;              // tk2 0..7 (token pair)
    const int w = t >> 6, lane = t & 63;
    const int khalf = lane >> 5, mn32 = lane & 31;

    const float gch = b2f(vec[256 + h * 32 + ch]);
    const float bch = b2f(vec[512 + h * 32 + ch]);
    const int tokbase = b * 4096 + chunk * 512;
    const float* xb = x2 + (size_t)tokbase * 256 + h * 32;

    f32x16 acc = {};
    for (int slab = 0; slab < 4; slab++) {
#pragma unroll
        for (int it = 0; it < 8; it++) {
            int tl = it * 16 + tk2 * 2;               // token in slab (even)
            int tok = slab * 128 + tl;                // token in chunk
            float2 st0 = stats[tokbase + tok];
            float2 st1 = stats[tokbase + tok + 1];
            float xv0 = xb[(size_t)tok * 256 + ch];
            float xv1 = xb[(size_t)(tok + 1) * 256 + ch];
            float e0 = __expf((xv0 - st0.x) * st0.y * gch + bch);
            float e1 = __expf((xv1 - st1.x) * st1.y * gch + bch);
            float s0 = e0, s1 = e1;
#pragma unroll
            for (int msk = 1; msk < 32; msk <<= 1) {
                s0 += __shfl_xor(s0, msk, 64);
                s1 += __shfl_xor(s1, msk, 64);
            }
            float qi0 = 1.0f / s0, qi1 = 1.0f / s1;
            unsigned int pe = (unsigned int)f2b(e0) | ((unsigned int)f2b(e1) << 16);
            unsigned int pq = (unsigned int)f2b(e0 * qi0) | ((unsigned int)f2b(e1 * qi1) << 16);
            *(unsigned int*)(E + ch * 132 + tl) = pe;
            *(unsigned int*)(Q + ch * 132 + tl) = pq;
        }
        __syncthreads();
        // wave w: tokens [w*32, w*32+32) of this slab -> 2 MFMA (K=16 each)
#pragma unroll
        for (int k16 = 0; k16 < 2; k16++) {
            int off = mn32 * 132 + w * 32 + k16 * 16 + khalf * 8;
            union { bf16x8 v; uint2 u[2]; } fa, fb;
            fa.u[0] = *(const uint2*)(Q + off);
            fa.u[1] = *(const uint2*)(Q + off + 4);
            fb.u[0] = *(const uint2*)(E + off);
            fb.u[1] = *(const uint2*)(E + off + 4);
            acc = __builtin_amdgcn_mfma_f32_32x32x16_bf16(fa.v, fb.v, acc, 0, 0, 0);
        }
        __syncthreads();
    }
    // cross-wave reduce: D layout col=lane&31, row=(reg&3)+8*(reg>>2)+4*(lane>>5)
    {
        float* R = Racc + w * 1024;
#pragma unroll
        for (int j = 0; j < 16; j++) {
            int row = (j & 3) + 8 * (j >> 2) + 4 * khalf;
            R[row * 32 + mn32] = acc[j];
        }
    }
    __syncthreads();
    {
        float4 s = make_float4(0.f, 0.f, 0.f, 0.f);
#pragma unroll
        for (int ww = 0; ww < 4; ww++) {
            float4 v = *(const float4*)(Racc + ww * 1024 + t * 4);
            s.x += v.x; s.y += v.y; s.z += v.z; s.w += v.w;
        }
        *(float4*)(ctxr + ((size_t)(bh * 8 + chunk) << 10) + t * 4) = s;
    }
}

// w2t[b][o][h*32+e] = (1/colsum[e]) * sum_d ctx[d,e]*rw[o,h*32+d]
// ctx = sum over 8 chunk slices; colsum[e] = sum_d ctx[d,e]
// grid 512 = (b(8), h(8), osplit(8))
__global__ __launch_bounds__(256) void k_w2(const float* __restrict__ ctxr,
                                            const unsigned short* __restrict__ rwb,
                                            unsigned short* __restrict__ w2t) {
    __shared__ float ctx_s[1024];   // [d][e]
    __shared__ float cinv[32];
    int blk = blockIdx.x;
    int b = blk >> 6, h = (blk >> 3) & 7, os = blk & 7;
    int bh = b * 8 + h;
    int t = threadIdx.x;
#pragma unroll
    for (int i = 0; i < 4; i++) {
        float s = 0.f;
#pragma unroll
        for (int c = 0; c < 8; c++)
            s += ctxr[((size_t)(bh * 8 + c) << 10) + t + 256 * i];
        ctx_s[t + 256 * i] = s;
    }
    __syncthreads();
    if (t < 32) {
        float s = 0.f;
#pragma unroll
        for (int d = 0; d < 32; d++) s += ctx_s[d * 32 + t];
        cinv[t] = 1.0f / s;
    }
    __syncthreads();
    int o = os * 64 + (t >> 2);
    int e0 = (t & 3) * 8;
    float wv[32];
    const uint4* wp = (const uint4*)(rwb + (size_t)o * 256 + h * 32);
#pragma unroll
    for (int qd = 0; qd < 4; qd++) {
        uint4 u = wp[qd];
        unsigned int uu[4] = {u.x, u.y, u.z, u.w};
#pragma unroll
        for (int j = 0; j < 4; j++) {
            wv[qd * 8 + j * 2]     = b2f((unsigned short)(uu[j] & 0xFFFFu));
            wv[qd * 8 + j * 2 + 1] = b2f((unsigned short)(uu[j] >> 16));
        }
    }
    float s[8];
#pragma unroll
    for (int j = 0; j < 8; j++) s[j] = 0.f;
#pragma unroll 8
    for (int d = 0; d < 32; d++) {
        float w = wv[d];
#pragma unroll
        for (int j = 0; j < 8; j++) s[j] += ctx_s[d * 32 + e0 + j] * w;
    }
    ushort4 o4a, o4b;
    o4a.x = f2b(s[0] * cinv[e0 + 0]); o4a.y = f2b(s[1] * cinv[e0 + 1]);
    o4a.z = f2b(s[2] * cinv[e0 + 2]); o4a.w = f2b(s[3] * cinv[e0 + 3]);
    o4b.x = f2b(s[4] * cinv[e0 + 4]); o4b.y = f2b(s[5] * cinv[e0 + 5]);
    o4b.z = f2b(s[6] * cinv[e0 + 6]); o4b.w = f2b(s[7] * cinv[e0 + 7]);
    unsigned short* dst = w2t + ((size_t)b * 512 + o) * 256 + h * 32 + e0;
    *(ushort4*)dst = o4a;
    *(ushort4*)(dst + 4) = o4b;
}

// GEMM1 + LN: n1 = LN(x1 @ W + lb) -> bf16 [32768][256]
// 512 thr / 8 waves; tile 128 rows x 256 cols; wave = 16 rows x 256 cols; BK=32
__global__ __launch_bounds__(512, 2) void k_gemm1(
    const float* __restrict__ x1, const unsigned short* __restrict__ wt1,
    const unsigned short* __restrict__ vec, unsigned short* __restrict__ n1) {
    __shared__ f32x4 pool4[2112];                  // 33792 B
    unsigned short* As = (unsigned short*)pool4;   // [128][40]
    unsigned short* Bs = As + 128 * 40;            // [256][40]
    unsigned short* n1s = (unsigned short*)pool4;  // [64][264] (epilogue)
    const int t = threadIdx.x;
    const int lane = t & 63, w = t >> 6;
    const int l15 = lane & 15, quad = lane >> 4;
    const int row0 = blockIdx.x * 128;
    const int mrow = w * 16 + l15;
    const int k8 = quad * 8;
    const int sm = t >> 2, sk = (t & 3) * 8;

    f32x4 acc[16];
#pragma unroll
    for (int i = 0; i < 16; i++) acc[i] = (f32x4){0.f, 0.f, 0.f, 0.f};

    for (int k0 = 0; k0 < 512; k0 += 32) {
        {   // A: 128x32 fp32 -> bf16
            const float* xf = x1 + (size_t)(row0 + sm) * 512 + k0 + sk;
            float4 f0 = *(const float4*)xf;
            float4 f1 = *(const float4*)(xf + 4);
            ushort4 lo, hi;
            lo.x = f2b(f0.x); lo.y = f2b(f0.y); lo.z = f2b(f0.z); lo.w = f2b(f0.w);
            hi.x = f2b(f1.x); hi.y = f2b(f1.y); hi.z = f2b(f1.z); hi.w = f2b(f1.w);
            *(ushort4*)(As + sm * 40 + sk) = lo;
            *(ushort4*)(As + sm * 40 + sk + 4) = hi;
        }
#pragma unroll
        for (int p = 0; p < 2; p++) {   // B: 256x32 bf16
            int n = sm + p * 128;
            *(uint4*)(Bs + n * 40 + sk) =
                *(const uint4*)(wt1 + (size_t)n * 512 + k0 + sk);
        }
        __syncthreads();
        bf16x8 a = *(const bf16x8*)(As + mrow * 40 + k8);
#pragma unroll
        for (int cb = 0; cb < 16; cb++) {
            bf16x8 bm = *(const bf16x8*)(Bs + ((cb << 4) + l15) * 40 + k8);
            acc[cb] = __builtin_amdgcn_mfma_f32_16x16x32_bf16(a, bm, acc[cb], 0, 0, 0);
        }
        __syncthreads();
    }
    // bias + LN(256), rows fully in-wave
#pragma unroll
    for (int cb = 0; cb < 16; cb++) {
        float bc = b2f(vec[(cb << 4) + l15]);
#pragma unroll
        for (int r = 0; r < 4; r++) acc[cb][r] += bc;
    }
    float mean_[4], rstd_[4];
#pragma unroll
    for (int r = 0; r < 4; r++) {
        float s = 0.f, q = 0.f;
#pragma unroll
        for (int cb = 0; cb < 16; cb++) { float v = acc[cb][r]; s += v; q += v * v; }
#pragma unroll
        for (int msk = 1; msk < 16; msk <<= 1) {
            s += __shfl_xor(s, msk, 64);
            q += __shfl_xor(q, msk, 64);
        }
        float mv = s * (1.0f / 256.0f);
        mean_[r] = mv;
        rstd_[r] = rsqrtf(q * (1.0f / 256.0f) - mv * mv + EPS);
    }
    // repack + coalesced store, two 64-row halves
#pragma unroll
    for (int half = 0; half < 2; half++) {
        if ((w >> 2) == half) {
            int rbase = (w & 3) * 16 + (quad << 2);
#pragma unroll
            for (int cb = 0; cb < 16; cb++) {
                int col = (cb << 4) + l15;
                float gg = b2f(vec[256 + col]), bbv = b2f(vec[512 + col]);
#pragma unroll
                for (int r = 0; r < 4; r++)
                    n1s[(rbase + r) * 264 + col] =
                        f2b((acc[cb][r] - mean_[r]) * rstd_[r] * gg + bbv);
            }
        }
        __syncthreads();
        {
            int rr = t >> 3, cc = (t & 7) * 32;
            const unsigned short* src = n1s + rr * 264 + cc;
            unsigned short* dst = n1 + (size_t)(row0 + half * 64 + rr) * 256 + cc;
#pragma unroll
            for (int j = 0; j < 4; j++)
                *(uint4*)(dst + j * 8) = *(const uint4*)(src + j * 8);
        }
        __syncthreads();
    }
}

// GEMM2 + bias + LN(512) + residual: out = LN(n1 @ w2t^T + rb)*ga + ba + x1
// 512 thr / 8 waves; tile 128 rows x 512 cols; wave = 16 rows x 512 cols; BK=32
__global__ __launch_bounds__(512, 2) void k_gemm2(
    const unsigned short* __restrict__ n1, const unsigned short* __restrict__ w2t,
    const unsigned short* __restrict__ vec, const float* __restrict__ x1,
    float* __restrict__ out) {
    __shared__ unsigned short As[128 * 40];    // 10240 B
    __shared__ unsigned short Bs[512 * 40];    // 40960 B
    const int t = threadIdx.x;
    const int lane = t & 63, w = t >> 6;
    const int l15 = lane & 15, quad = lane >> 4;
    const int row0 = blockIdx.x * 128;
    const unsigned short* wb = w2t + (size_t)(row0 >> 12) * (512 * 256);
    const int mrow = w * 16 + l15;
    const int k8 = quad * 8;
    const int sm = t >> 2, sk = (t & 3) * 8;

    f32x4 acc[32];
#pragma unroll
    for (int i = 0; i < 32; i++) acc[i] = (f32x4){0.f, 0.f, 0.f, 0.f};

    for (int k0 = 0; k0 < 256; k0 += 32) {
        *(uint4*)(As + sm * 40 + sk) =
            *(const uint4*)(n1 + (size_t)(row0 + sm) * 256 + k0 + sk);
#pragma unroll
        for (int p = 0; p < 4; p++) {
            int n = sm + p * 128;
            *(uint4*)(Bs + n * 40 + sk) =
                *(const uint4*)(wb + (size_t)n * 256 + k0 + sk);
        }
        __syncthreads();
        bf16x8 a = *(const bf16x8*)(As + mrow * 40 + k8);
#pragma unroll
        for (int cb = 0; cb < 32; cb++) {
            bf16x8 bm = *(const bf16x8*)(Bs + ((cb << 4) + l15) * 40 + k8);
            acc[cb] = __builtin_amdgcn_mfma_f32_16x16x32_bf16(a, bm, acc[cb], 0, 0, 0);
        }
        __syncthreads();
    }
    // + rb, LN(512) fully in-wave
#pragma unroll
    for (int cb = 0; cb < 32; cb++) {
        float bc = b2f(vec[768 + (cb << 4) + l15]);
#pragma unroll
        for (int r = 0; r < 4; r++) acc[cb][r] += bc;
    }
    float mean_[4], rstd_[4];
#pragma unroll
    for (int r = 0; r < 4; r++) {
        float s = 0.f, q = 0.f;
#pragma unroll
        for (int cb = 0; cb < 32; cb++) { float v = acc[cb][r]; s += v; q += v * v; }
#pragma unroll
        for (int msk = 1; msk < 16; msk <<= 1) {
            s += __shfl_xor(s, msk, 64);
            q += __shfl_xor(q, msk, 64);
        }
        float mv = s * (1.0f / 512.0f);
        mean_[r] = mv;
        rstd_[r] = rsqrtf(q * (1.0f / 512.0f) - mv * mv + EPS);
    }
#pragma unroll
    for (int cb = 0; cb < 32; cb++) {
        int col = (cb << 4) + l15;
        float gg = b2f(vec[1280 + col]), bbv = b2f(vec[1792 + col]);
#pragma unroll
        for (int r = 0; r < 4; r++) {
            size_t idx = (size_t)(row0 + w * 16 + (quad << 2) + r) * 512 + col;
            out[idx] = (acc[cb][r] - mean_[r]) * rstd_[r] * gg + bbv + x1[idx];
        }
    }
}

extern "C" void kernel_launch(void* const* d_in, const int* in_sizes, int n_in,
                              void* d_out, int out_size, void* d_ws, size_t ws_size,
                              hipStream_t stream) {
    const float* x1 = (const float*)d_in[0];
    const float* x2 = (const float*)d_in[1];
    const float* lw = (const float*)d_in[2];
    const float* lb = (const float*)d_in[3];
    const float* g1 = (const float*)d_in[4];
    const float* b1 = (const float*)d_in[5];
    const float* rw = (const float*)d_in[6];
    const float* rb = (const float*)d_in[7];
    const float* ga = (const float*)d_in[8];
    const float* ba = (const float*)d_in[9];
    float* out = (float*)d_out;

    char* ws = (char*)d_ws;
    float*          ctxr  = (float*)(ws);                       // 2 MB  [64][8][1024]
    float2*         stats = (float2*)(ws + 2097152);            // 256 KB
    unsigned short* wt1   = (unsigned short*)(ws + 2359296);    // 256 KB
    unsigned short* rwb   = (unsigned short*)(ws + 2621440);    // 256 KB
    unsigned short* vec   = (unsigned short*)(ws + 2883584);    // 4.5 KB (pad 8K)
    unsigned short* w2t   = (unsigned short*)(ws + 2891776);    // 2 MB
    unsigned short* n1    = (unsigned short*)(ws + 4988928);    // 16 MB (total ~21 MB)

    k_params<<<dim3(1033), dim3(256), 0, stream>>>(lw, rw, lb, g1, b1, rb, ga, ba,
                                                   wt1, rwb, vec);
    k_stats<<<dim3(8192), dim3(256), 0, stream>>>(x2, stats);
    k_ctx<<<dim3(512), dim3(256), 0, stream>>>(x2, stats, vec, ctxr);
    k_w2<<<dim3(512), dim3(256), 0, stream>>>(ctxr, rwb, w2t);
    k_gemm1<<<dim3(256), dim3(512), 0, stream>>>(x1, wt1, vec, n1);
    k_gemm2<<<dim3(256), dim3(512), 0, stream>>>(n1, w2t, vec, x1, out);
}